// Round 6
// baseline (503.497 us; speedup 1.0000x reference)
//
#include <hip/hip_runtime.h>
#include <hip/hip_bf16.h>
#include <math.h>

typedef __attribute__((ext_vector_type(8))) short bf16x8;
typedef __attribute__((ext_vector_type(4))) float f32x4;

// Raw workgroup barrier WITHOUT the vmcnt(0) drain that __syncthreads() emits.
// Orders LDS only (lgkmcnt). Global prefetch loads stay in flight across it.
__device__ __forceinline__ void wg_barrier() {
    asm volatile("s_waitcnt lgkmcnt(0)" ::: "memory");
    __builtin_amdgcn_s_barrier();
    asm volatile("" ::: "memory");
}

// ---------------- qkv projection: q/k/v = X @ W + b (f32 out to ws) ----------
__global__ void qkv_proj_kernel(const float* __restrict__ query,
                                const float* __restrict__ key,
                                const float* __restrict__ value,
                                const float* __restrict__ Wq, const float* __restrict__ bq,
                                const float* __restrict__ Wk, const float* __restrict__ bk,
                                const float* __restrict__ Wv, const float* __restrict__ bv,
                                float* __restrict__ qf, float* __restrict__ kf,
                                float* __restrict__ vf)
{
    const int mat = blockIdx.x >> 8;
    const int rb  = blockIdx.x & 255;
    const float* X; const float* W; const float* bias; float* dst;
    if (mat == 0)      { X = query; W = Wq; bias = bq; dst = qf; }
    else if (mat == 1) { X = key;   W = Wk; bias = bk; dst = kf; }
    else               { X = value; W = Wv; bias = bv; dst = vf; }

    __shared__ float sX[16][128];
    const int tid = threadIdx.x;
    const float* src = X + (size_t)rb * 16 * 128;
    #pragma unroll
    for (int i = 0; i < 8; ++i) {
        int idx = tid + i * 256;
        sX[idx >> 7][idx & 127] = src[idx];
    }
    __syncthreads();

    const int col = tid & 127;
    const int rg  = tid >> 7;
    float acc[8] = {0.f,0.f,0.f,0.f,0.f,0.f,0.f,0.f};
    for (int e = 0; e < 128; ++e) {
        float w = W[e * 128 + col];
        #pragma unroll
        for (int r = 0; r < 8; ++r) acc[r] += sX[rg * 8 + r][e] * w;
    }
    float bb = bias[col];
    #pragma unroll
    for (int r = 0; r < 8; ++r)
        dst[(size_t)(rb * 16 + rg * 8 + r) * 128 + col] = acc[r] + bb;
}

// ---------------- fused main kernel: one workgroup per (b, n) ----------------
// score_pe[m,h] = relpe[m,:] . Wtilde[:,h],  Wtilde = Wpe_hblock @ (q_h/SCALE)
// out_pe[h,:]   = (sum_m P[m,h] relpe[m,:]) @ Wpe_hblock
// In-loop barriers are raw (no vmcnt drain) so the next-tile rel_pe prefetch
// stays in flight across GEMM1/softmax/GEMM2 — that drain was the R2-R5 limiter.
__global__ __launch_bounds__(256, 4) void mha_main_kernel(
    const float* __restrict__ relpe,
    const float* __restrict__ mask,
    const float* __restrict__ qf,
    const float* __restrict__ kf,
    const float* __restrict__ vf,
    const float* __restrict__ Wpe, const float* __restrict__ bpe,
    const float* __restrict__ Wo,  const float* __restrict__ bo,
    float* __restrict__ out)
{
    __shared__ __hip_bfloat16 sA[64][136];   // rel_pe tile bf16
    __shared__ __hip_bfloat16 sWt[16][136];  // sWt[h][e] = Wtilde[e][h]
    __shared__ __hip_bfloat16 sPb[16][72];   // P bf16, [h][m]
    __shared__ float sS[8][258];             // scores (padded: stride 258); epilogue: pr
    __shared__ float sPf[8][68];             // P f32 (padded)
    __shared__ float sQs[128];
    __shared__ float sCb[8];
    __shared__ float sM[8], sL[8];
    __shared__ float sRf[16];
    __shared__ float sRed[128];
    __shared__ float sOut[128];

    const int tid  = threadIdx.x;
    const int lane = tid & 63;
    const int wv   = tid >> 6;
    const int bid  = ((blockIdx.x & 7) << 9) | (blockIdx.x >> 3);  // XCD swizzle
    const int b    = bid >> 8;
    const int n    = bid & 255;
    const size_t bn = (size_t)(b * 256 + n);

    // ---- issue tile-0 prefetch first; no drain until the stage-write uses it
    float4 pf[8];
    {
        const float4* s4 = (const float4*)(relpe + (bn * 256) * 128);
        #pragma unroll
        for (int i = 0; i < 8; ++i) pf[i] = s4[tid + i * 256];
    }

    if (tid < 128) sQs[tid] = qf[bn * 128 + tid] * 0.25f;
    if (tid < 8)  { sM[tid] = -INFINITY; sL[tid] = 0.f; }
    if (tid < 16) sRf[tid] = 1.f;
    if (tid < 72) {
        #pragma unroll
        for (int r = 8; r < 16; ++r) sPb[r][tid] = __float2bfloat16(0.f);
    }
    if (tid < 128) {
        #pragma unroll
        for (int r = 8; r < 16; ++r) sWt[r][tid] = __float2bfloat16(0.f);
    }
    wg_barrier();   // sQs ready; tile-0 loads still in flight

    // ---- Wtilde[e][h] (stored transposed)
    #pragma unroll
    for (int o = tid; o < 1024; o += 256) {
        int h = o >> 7, e = o & 127;
        const float4* wr = (const float4*)(Wpe + (size_t)e * 128 + h * 16);
        float4 w0 = wr[0], w1 = wr[1], w2 = wr[2], w3 = wr[3];
        const float* qh = &sQs[h * 16];
        float acc = w0.x*qh[0]+w0.y*qh[1]+w0.z*qh[2]+w0.w*qh[3]
                  + w1.x*qh[4]+w1.y*qh[5]+w1.z*qh[6]+w1.w*qh[7]
                  + w2.x*qh[8]+w2.y*qh[9]+w2.z*qh[10]+w2.w*qh[11]
                  + w3.x*qh[12]+w3.y*qh[13]+w3.z*qh[14]+w3.w*qh[15];
        sWt[h][e] = __float2bfloat16(acc);
    }
    if (tid < 8) {
        float acc = 0.f;
        #pragma unroll
        for (int d = 0; d < 16; ++d) acc += bpe[tid * 16 + d] * sQs[tid * 16 + d];
        sCb[tid] = acc;
    }

    const int hsc = tid >> 5;
    const int ml  = tid & 31;
    // ---- prologue qk scores (once)
    #pragma unroll
    for (int i = 0; i < 8; ++i) {
        int m = i * 32 + ml;
        const float4* k4 = (const float4*)(kf + ((size_t)(b * 256) + m) * 128 + hsc * 16);
        float4 ka = k4[0], kb = k4[1], kc = k4[2], kd = k4[3];
        const float* qh = &sQs[hsc * 16];
        float s = ka.x*qh[0]+ka.y*qh[1]+ka.z*qh[2]+ka.w*qh[3]
                + kb.x*qh[4]+kb.y*qh[5]+kb.z*qh[6]+kb.w*qh[7]
                + kc.x*qh[8]+kc.y*qh[9]+kc.z*qh[10]+kc.w*qh[11]
                + kd.x*qh[12]+kd.y*qh[13]+kd.z*qh[14]+kd.w*qh[15];
        sS[hsc][m] = s + mask[bn * 256 + m];
    }

    // ---- write tile 0 to sA (compiler inserts precise vmcnt waits for pf)
    #pragma unroll
    for (int i = 0; i < 8; ++i) {
        int idx4 = tid + i * 256;
        int lr = idx4 >> 5, c4 = (idx4 & 31) * 4;
        __hip_bfloat162* dp = (__hip_bfloat162*)&sA[lr][c4];
        dp[0] = __float22bfloat162_rn(make_float2(pf[i].x, pf[i].y));
        dp[1] = __float22bfloat162_rn(make_float2(pf[i].z, pf[i].w));
    }
    wg_barrier();

    float out_acc = 0.f;
    f32x4 pr0 = {}, pr1 = {};
    const int e     = tid & 127;
    const int halfp = tid >> 7;
    const int hh    = e >> 4;
    const int arow  = lane & 15;
    const int koff  = lane >> 4;

    for (int t = 0; t < 4; ++t) {
        // issue next tile's loads; they stay in flight across ALL raw barriers
        if (t < 3) {
            const float4* s4 = (const float4*)(relpe + (bn * 256 + (t + 1) * 64) * 128);
            #pragma unroll
            for (int i = 0; i < 8; ++i) pf[i] = s4[tid + i * 256];
        }

        // ---- GEMM1: score = (qk+mask) + cb + relpe_tile @ Wtilde
        f32x4 cs;
        #pragma unroll
        for (int r = 0; r < 4; ++r) {
            int row = wv * 16 + koff * 4 + r;
            cs[r] = (arow < 8) ? (sS[arow][t * 64 + row] + sCb[arow]) : 0.f;
        }
        #pragma unroll
        for (int kt = 0; kt < 4; ++kt) {
            bf16x8 af  = *(const bf16x8*)&sA[wv * 16 + arow][kt * 32 + koff * 8];
            bf16x8 bfr = *(const bf16x8*)&sWt[arow][kt * 32 + koff * 8];
            cs = __builtin_amdgcn_mfma_f32_16x16x32_bf16(af, bfr, cs, 0, 0, 0);
        }
        if (arow < 8) {
            #pragma unroll
            for (int r = 0; r < 4; ++r)
                sS[arow][t * 64 + wv * 16 + koff * 4 + r] = cs[r];
        }
        wg_barrier();

        // ---- softmax (LDS-only)
        {
            float sc0 = sS[hsc][t * 64 + ml];
            float sc1 = sS[hsc][t * 64 + ml + 32];
            float tm = fmaxf(sc0, sc1);
            #pragma unroll
            for (int m2 = 16; m2 >= 1; m2 >>= 1) tm = fmaxf(tm, __shfl_xor(tm, m2, 32));
            float mold = sM[hsc];
            float mnew = fmaxf(mold, tm);
            float p0 = __expf(sc0 - mnew), p1 = __expf(sc1 - mnew);
            float ts = p0 + p1;
            #pragma unroll
            for (int m2 = 16; m2 >= 1; m2 >>= 1) ts += __shfl_xor(ts, m2, 32);
            if (ml == 0) {
                float rf = __expf(mold - mnew);
                sRf[hsc] = rf;
                sM[hsc]  = mnew;
                sL[hsc]  = sL[hsc] * rf + ts;
            }
            sPf[hsc][ml]      = p0;
            sPf[hsc][ml + 32] = p1;
            sPb[hsc][ml]      = __float2bfloat16(p0);
            sPb[hsc][ml + 32] = __float2bfloat16(p1);
        }
        wg_barrier();

        // ---- GEMM2: pr += P^T @ relpe_tile; VALU PV for v
        {
            #pragma unroll
            for (int r = 0; r < 4; ++r) {
                float rf = sRf[koff * 4 + r];
                pr0[r] *= rf; pr1[r] *= rf;
            }
            #pragma unroll
            for (int kt = 0; kt < 2; ++kt) {
                bf16x8 ap = *(const bf16x8*)&sPb[arow][kt * 32 + koff * 8];
                bf16x8 b0, b1;
                #pragma unroll
                for (int j = 0; j < 8; ++j) {
                    int row = kt * 32 + koff * 8 + j;
                    b0[j] = *(const short*)&sA[row][wv * 32 + arow];
                    b1[j] = *(const short*)&sA[row][wv * 32 + 16 + arow];
                }
                pr0 = __builtin_amdgcn_mfma_f32_16x16x32_bf16(ap, b0, pr0, 0, 0, 0);
                pr1 = __builtin_amdgcn_mfma_f32_16x16x32_bf16(ap, b1, pr1, 0, 0, 0);
            }
            out_acc *= sRf[hh];
            const float* vp = vf + ((size_t)(b * 256) + t * 64 + halfp * 32) * 128 + e;
            const float4* pp4 = (const float4*)&sPf[hh][halfp * 32];
            #pragma unroll
            for (int ii = 0; ii < 8; ++ii) {
                float4 p4 = pp4[ii];
                out_acc += p4.x * vp[(size_t)(4*ii+0) * 128] + p4.y * vp[(size_t)(4*ii+1) * 128]
                         + p4.z * vp[(size_t)(4*ii+2) * 128] + p4.w * vp[(size_t)(4*ii+3) * 128];
            }
        }
        wg_barrier();   // all sA reads done

        if (t < 3) {
            #pragma unroll
            for (int i = 0; i < 8; ++i) {
                int idx4 = tid + i * 256;
                int lr = idx4 >> 5, c4 = (idx4 & 31) * 4;
                __hip_bfloat162* dp = (__hip_bfloat162*)&sA[lr][c4];
                dp[0] = __float22bfloat162_rn(make_float2(pf[i].x, pf[i].y));
                dp[1] = __float22bfloat162_rn(make_float2(pf[i].z, pf[i].w));
            }
            wg_barrier();
        }
    }

    // ---- epilogue (reuse sS rows 0-7 for pr) — plain __syncthreads is fine here
    if (halfp) sRed[e] = out_acc;
    #pragma unroll
    for (int r = 0; r < 4; ++r) {
        int row = koff * 4 + r;
        if (row < 8) {
            sS[row][wv * 32 + arow]      = pr0[r];
            sS[row][wv * 32 + 16 + arow] = pr1[r];
        }
    }
    __syncthreads();
    float outv = out_acc + (halfp ? 0.f : sRed[e]);
    __syncthreads();

    float ype = 0.f;
    {
        const float* wp  = Wpe + (size_t)(halfp * 64) * 128 + e;
        const float* prh = &sS[hh][halfp * 64];
        #pragma unroll 8
        for (int ee = 0; ee < 64; ++ee) ype += prh[ee] * wp[(size_t)ee * 128];
    }
    if (halfp) sRed[e] = ype;
    __syncthreads();
    if (!halfp) sOut[e] = (outv + ype + sRed[e]) / sL[hh] + bpe[e];
    __syncthreads();

    float y = 0.f;
    {
        const float* wo = Wo + (size_t)(halfp * 64) * 128 + e;
        #pragma unroll 8
        for (int ee = 0; ee < 64; ++ee) y += sOut[halfp * 64 + ee] * wo[(size_t)ee * 128];
    }
    if (halfp) sRed[e] = y;
    __syncthreads();
    if (!halfp) out[bn * 128 + e] = y + sRed[e] + bo[e];
}

extern "C" void kernel_launch(void* const* d_in, const int* in_sizes, int n_in,
                              void* d_out, int out_size, void* d_ws, size_t ws_size,
                              hipStream_t stream)
{
    const float* query = (const float*)d_in[0];
    const float* key   = (const float*)d_in[1];
    const float* value = (const float*)d_in[2];
    const float* relpe = (const float*)d_in[3];
    const float* mask  = (const float*)d_in[4];
    const float* Wq  = (const float*)d_in[5];
    const float* bq  = (const float*)d_in[6];
    const float* Wk  = (const float*)d_in[7];
    const float* bk  = (const float*)d_in[8];
    const float* Wv  = (const float*)d_in[9];
    const float* bv  = (const float*)d_in[10];
    const float* Wpe = (const float*)d_in[11];
    const float* bpe = (const float*)d_in[12];
    const float* Wo  = (const float*)d_in[13];
    const float* bo  = (const float*)d_in[14];
    float* out = (float*)d_out;

    float* qf = (float*)d_ws;
    float* kf = qf + 16 * 256 * 128;
    float* vf = kf + 16 * 256 * 128;

    qkv_proj_kernel<<<dim3(768), dim3(256), 0, stream>>>(
        query, key, value, Wq, bq, Wk, bk, Wv, bv, qf, kf, vf);
    mha_main_kernel<<<dim3(4096), dim3(256), 0, stream>>>(
        relpe, mask, qf, kf, vf, Wpe, bpe, Wo, bo, out);
}

// Round 7
// 304.852 us; speedup vs baseline: 1.6516x; 1.6516x over previous
//
#include <hip/hip_runtime.h>
#include <hip/hip_bf16.h>
#include <math.h>

typedef __attribute__((ext_vector_type(8))) short bf16x8;
typedef __attribute__((ext_vector_type(4))) float f32x4;

// ---------------- qkv projection: q/k/v = X @ W + b (f32 out to ws) ----------
__global__ void qkv_proj_kernel(const float* __restrict__ query,
                                const float* __restrict__ key,
                                const float* __restrict__ value,
                                const float* __restrict__ Wq, const float* __restrict__ bq,
                                const float* __restrict__ Wk, const float* __restrict__ bk,
                                const float* __restrict__ Wv, const float* __restrict__ bv,
                                float* __restrict__ qf, float* __restrict__ kf,
                                float* __restrict__ vf)
{
    const int mat = blockIdx.x >> 8;
    const int rb  = blockIdx.x & 255;
    const float* X; const float* W; const float* bias; float* dst;
    if (mat == 0)      { X = query; W = Wq; bias = bq; dst = qf; }
    else if (mat == 1) { X = key;   W = Wk; bias = bk; dst = kf; }
    else               { X = value; W = Wv; bias = bv; dst = vf; }

    __shared__ float sX[16][128];
    const int tid = threadIdx.x;
    const float* src = X + (size_t)rb * 16 * 128;
    #pragma unroll
    for (int i = 0; i < 8; ++i) {
        int idx = tid + i * 256;
        sX[idx >> 7][idx & 127] = src[idx];
    }
    __syncthreads();

    const int col = tid & 127;
    const int rg  = tid >> 7;
    float acc[8] = {0.f,0.f,0.f,0.f,0.f,0.f,0.f,0.f};
    for (int e = 0; e < 128; ++e) {
        float w = W[e * 128 + col];
        #pragma unroll
        for (int r = 0; r < 8; ++r) acc[r] += sX[rg * 8 + r][e] * w;
    }
    float bb = bias[col];
    #pragma unroll
    for (int r = 0; r < 8; ++r)
        dst[(size_t)(rb * 16 + rg * 8 + r) * 128 + col] = acc[r] + bb;
}

// ---------------- fused main kernel: wave-autonomous --------------------------
// One workgroup per (b,n); wave w owns m-rows [w*64, w*64+64) as 2x32-row
// subtiles. NO barriers in the main body: each wave stages/computes in its own
// LDS region; compiler emits precise counted vmcnt/lgkmcnt, so HBM prefetch of
// the next subtile stays in flight under compute. Cross-wave only at prologue
// (shared Wtilde) and a flash-style combine epilogue.
__global__ __launch_bounds__(256) void mha_main_kernel(
    const float* __restrict__ relpe,
    const float* __restrict__ mask,
    const float* __restrict__ qf,
    const float* __restrict__ kf,
    const float* __restrict__ vf,
    const float* __restrict__ Wpe, const float* __restrict__ bpe,
    const float* __restrict__ Wo,  const float* __restrict__ bo,
    float* __restrict__ out)
{
    __shared__ __align__(16) char smem[59424];
    const int tid  = threadIdx.x;
    const int lane = tid & 63;
    const int wv   = tid >> 6;
    const int bid  = ((blockIdx.x & 7) << 9) | (blockIdx.x >> 3);  // XCD swizzle
    const int b    = bid >> 8;
    const int n    = bid & 255;
    const size_t bn = (size_t)(b * 256 + n);

    // per-wave region (13568 B each)
    char* wb = smem + wv * 13568;
    __hip_bfloat16* sA  = (__hip_bfloat16*)wb;             // [32][136] relpe subtile bf16
    float*          sQK = (float*)(wb + 8704);             // [64][9] qk+cb+mask scores
    __hip_bfloat16* sP  = (__hip_bfloat16*)(wb + 11008);   // [16][40] P bf16 (h-major)
    float*          sPf = (float*)(wb + 12288);            // [32][9] P f32 (m-major)
    float*          sRf = (float*)(wb + 13440);            // [16] rescale per head
    // shared
    float*          sQs = (float*)(smem + 54272);          // [128] q/SCALE
    __hip_bfloat16* sWt = (__hip_bfloat16*)(smem + 54784); // [16][136] Wtilde^T
    float*          sCb = (float*)(smem + 59136);          // [8]
    float*          sMLm= (float*)(smem + 59168);          // [4][8]
    float*          sMLl= (float*)(smem + 59296);          // [4][8]

    if (tid < 128) sQs[tid] = qf[bn * 128 + tid] * 0.25f;
    __syncthreads();   // barrier 1 (prologue)

    // ---- Wtilde[e][h] = Wpe[e][16h..] . q_h/SCALE, stored transposed
    #pragma unroll
    for (int o = tid; o < 1024; o += 256) {
        int h = o >> 7, e = o & 127;
        const float4* wr = (const float4*)(Wpe + (size_t)e * 128 + h * 16);
        float4 w0 = wr[0], w1 = wr[1], w2 = wr[2], w3 = wr[3];
        const float* qh = sQs + h * 16;
        float acc = w0.x*qh[0]+w0.y*qh[1]+w0.z*qh[2]+w0.w*qh[3]
                  + w1.x*qh[4]+w1.y*qh[5]+w1.z*qh[6]+w1.w*qh[7]
                  + w2.x*qh[8]+w2.y*qh[9]+w2.z*qh[10]+w2.w*qh[11]
                  + w3.x*qh[12]+w3.y*qh[13]+w3.z*qh[14]+w3.w*qh[15];
        sWt[h * 136 + e] = __float2bfloat16(acc);
    }
    if (tid < 128) {
        #pragma unroll
        for (int r = 8; r < 16; ++r) sWt[r * 136 + tid] = __float2bfloat16(0.f);
    }
    if (tid < 8) {
        float acc = 0.f;
        #pragma unroll
        for (int d = 0; d < 16; ++d) acc += bpe[tid * 16 + d] * sQs[tid * 16 + d];
        sCb[tid] = acc;
    }
    __syncthreads();   // barrier 2 (prologue) — only L2 loads drained

    const int mw = wv * 64;

    // ---- qk + cb + mask for the wave's 64 rows (coalesced: lane = row-octet x head)
    {
        const int hq = lane & 7;
        const int rg = lane >> 3;
        float qreg[16];
        #pragma unroll
        for (int i = 0; i < 4; ++i)
            ((float4*)qreg)[i] = ((const float4*)(sQs + hq * 16))[i];
        float cb = sCb[hq];
        #pragma unroll
        for (int p = 0; p < 8; ++p) {
            int row = p * 8 + rg;
            const float4* kr = (const float4*)(kf + ((size_t)(b * 256) + mw + row) * 128 + hq * 16);
            float4 k0 = kr[0], k1 = kr[1], k2 = kr[2], k3 = kr[3];
            float s = k0.x*qreg[0]+k0.y*qreg[1]+k0.z*qreg[2]+k0.w*qreg[3]
                    + k1.x*qreg[4]+k1.y*qreg[5]+k1.z*qreg[6]+k1.w*qreg[7]
                    + k2.x*qreg[8]+k2.y*qreg[9]+k2.z*qreg[10]+k2.w*qreg[11]
                    + k3.x*qreg[12]+k3.y*qreg[13]+k3.z*qreg[14]+k3.w*qreg[15];
            sQK[row * 9 + hq] = s + cb + mask[bn * 256 + mw + row];
        }
    }

    // ---- issue subtile-0 HBM loads (after qk so ordered vmcnt doesn't couple them)
    float4 pf[16];
    {
        const float4* rp = (const float4*)(relpe + (bn * 256 + mw) * 128);
        #pragma unroll
        for (int i = 0; i < 16; ++i) pf[i] = rp[i * 64 + lane];
    }

    const int arow = lane & 15;
    const int koff = lane >> 4;
    float m_run = -INFINITY, l_run = 0.f;
    f32x4 pr[8] = {};
    float oa0 = 0.f, oa1 = 0.f;

    #pragma unroll
    for (int st = 0; st < 2; ++st) {
        // ---- stage current subtile (precise vmcnt wait on pf only)
        #pragma unroll
        for (int i = 0; i < 16; ++i) {
            int row = 2 * i + (lane >> 5);
            int col = (lane & 31) * 4;
            union { __hip_bfloat162 h2[2]; uint2 u; } pk;
            pk.h2[0] = __float22bfloat162_rn(make_float2(pf[i].x, pf[i].y));
            pk.h2[1] = __float22bfloat162_rn(make_float2(pf[i].z, pf[i].w));
            *(uint2*)&sA[row * 136 + col] = pk.u;
        }
        // ---- issue next subtile (in flight across all of this subtile's compute)
        if (st == 0) {
            const float4* rp = (const float4*)(relpe + (bn * 256 + mw + 32) * 128);
            #pragma unroll
            for (int i = 0; i < 16; ++i) pf[i] = rp[i * 64 + lane];
        }

        // ---- GEMM1: scores = qk + relpe @ Wtilde  (C rows = m, cols = h)
        f32x4 cs0, cs1;
        #pragma unroll
        for (int r = 0; r < 4; ++r) {
            int rb0 = st * 32 + koff * 4 + r;
            cs0[r] = (arow < 8) ? sQK[rb0 * 9 + arow] : 0.f;
            cs1[r] = (arow < 8) ? sQK[(rb0 + 16) * 9 + arow] : 0.f;
        }
        #pragma unroll
        for (int kt = 0; kt < 4; ++kt) {
            bf16x8 bw = *(const bf16x8*)&sWt[arow * 136 + kt * 32 + koff * 8];
            bf16x8 a0 = *(const bf16x8*)&sA[arow * 136 + kt * 32 + koff * 8];
            bf16x8 a1 = *(const bf16x8*)&sA[(16 + arow) * 136 + kt * 32 + koff * 8];
            cs0 = __builtin_amdgcn_mfma_f32_16x16x32_bf16(a0, bw, cs0, 0, 0, 0);
            cs1 = __builtin_amdgcn_mfma_f32_16x16x32_bf16(a1, bw, cs1, 0, 0, 0);
        }

        // ---- per-wave online softmax (head h = arow; groups combined via xor 16/32)
        float tm = fmaxf(fmaxf(fmaxf(cs0[0], cs0[1]), fmaxf(cs0[2], cs0[3])),
                         fmaxf(fmaxf(cs1[0], cs1[1]), fmaxf(cs1[2], cs1[3])));
        tm = fmaxf(tm, __shfl_xor(tm, 16));
        tm = fmaxf(tm, __shfl_xor(tm, 32));
        float mnew = fmaxf(m_run, tm);
        float p0[4], p1[4]; float ts = 0.f;
        #pragma unroll
        for (int r = 0; r < 4; ++r) {
            p0[r] = __expf(cs0[r] - mnew); ts += p0[r];
            p1[r] = __expf(cs1[r] - mnew); ts += p1[r];
        }
        ts += __shfl_xor(ts, 16);
        ts += __shfl_xor(ts, 32);
        float rf = __expf(m_run - mnew);
        l_run = l_run * rf + ts;
        m_run = mnew;
        if (koff == 0) sRf[arow] = rf;

        // ---- write P (bf16 h-major for GEMM2-A; f32 m-major for PV)
        #pragma unroll
        for (int r = 0; r < 4; ++r) {
            int ml0 = koff * 4 + r;
            sP[arow * 40 + ml0]      = __float2bfloat16(p0[r]);
            sP[arow * 40 + ml0 + 16] = __float2bfloat16(p1[r]);
            if (arow < 8) {
                sPf[ml0 * 9 + arow]        = p0[r];
                sPf[(ml0 + 16) * 9 + arow] = p1[r];
            }
        }

        // ---- rescale running accumulators
        float rfr[4];
        #pragma unroll
        for (int r = 0; r < 4; ++r) rfr[r] = sRf[koff * 4 + r];
        #pragma unroll
        for (int es = 0; es < 8; ++es) {
            #pragma unroll
            for (int r = 0; r < 4; ++r) pr[es][r] *= rfr[r];
        }
        float rpv = sRf[lane >> 3];
        oa0 *= rpv; oa1 *= rpv;

        // ---- GEMM2: pr[h][e] += P^T @ relpe_subtile (K=32)
        bf16x8 ap = *(const bf16x8*)&sP[arow * 40 + koff * 8];
        #pragma unroll
        for (int es = 0; es < 8; ++es) {
            bf16x8 bv;
            #pragma unroll
            for (int j = 0; j < 8; ++j)
                bv[j] = *(const short*)&sA[(koff * 8 + j) * 136 + es * 16 + arow];
            pr[es] = __builtin_amdgcn_mfma_f32_16x16x32_bf16(ap, bv, pr[es], 0, 0, 0);
        }

        // ---- PV (v from L2): lane covers e = 2*lane, 2*lane+1; head = lane>>3
        const float* vp = vf + ((size_t)(b * 256) + mw + st * 32) * 128 + 2 * lane;
        const int hpv = lane >> 3;
        #pragma unroll
        for (int mm = 0; mm < 32; ++mm) {
            float2 v2 = *(const float2*)(vp + (size_t)mm * 128);
            float pw = sPf[mm * 9 + hpv];
            oa0 += pw * v2.x; oa1 += pw * v2.y;
        }
    }

    // ================= flash-style cross-wave combine epilogue =================
    if (koff == 0 && arow < 8) { sMLm[wv * 8 + arow] = m_run; sMLl[wv * 8 + arow] = l_run; }
    __syncthreads();

    float* sPrAcc = (float*)smem;              // [4][8][128]
    float* sOutAcc = (float*)(smem + 16384);   // [4][128]
    #pragma unroll
    for (int r = 0; r < 4; ++r) {
        int hrow = koff * 4 + r;
        if (hrow < 8) {
            float M = fmaxf(fmaxf(sMLm[hrow], sMLm[8 + hrow]),
                            fmaxf(sMLm[16 + hrow], sMLm[24 + hrow]));
            float sc = __expf(sMLm[wv * 8 + hrow] - M);
            #pragma unroll
            for (int es = 0; es < 8; ++es)
                sPrAcc[(wv * 8 + hrow) * 128 + es * 16 + arow] = pr[es][r] * sc;
        }
    }
    {
        int hpv = lane >> 3;
        float M = fmaxf(fmaxf(sMLm[hpv], sMLm[8 + hpv]),
                        fmaxf(sMLm[16 + hpv], sMLm[24 + hpv]));
        float sc = __expf(sMLm[wv * 8 + hpv] - M);
        sOutAcc[wv * 128 + 2 * lane]     = oa0 * sc;
        sOutAcc[wv * 128 + 2 * lane + 1] = oa1 * sc;
    }
    __syncthreads();

    float* sPrS  = (float*)(smem + 18432);     // [8][128]
    float* sOutS = (float*)(smem + 22528);     // [128]
    #pragma unroll
    for (int i = 0; i < 4; ++i) {
        int idx = tid + 256 * i;
        sPrS[idx] = sPrAcc[idx] + sPrAcc[1024 + idx] + sPrAcc[2048 + idx] + sPrAcc[3072 + idx];
    }
    if (tid < 128)
        sOutS[tid] = sOutAcc[tid] + sOutAcc[128 + tid] + sOutAcc[256 + tid] + sOutAcc[384 + tid];
    __syncthreads();

    float* sRed  = (float*)(smem + 23040);     // [128]
    float* sOutF = (float*)(smem + 23552);     // [128]
    const int e = tid & 127, half = tid >> 7, hh = e >> 4;
    float ype = 0.f;
    {
        const float* wp  = Wpe + (size_t)(half * 64) * 128 + e;
        const float* prh = &sPrS[hh * 128 + half * 64];
        #pragma unroll 8
        for (int ee = 0; ee < 64; ++ee) ype += prh[ee] * wp[(size_t)ee * 128];
    }
    if (half) sRed[e] = ype;
    __syncthreads();
    if (!half) {
        float M = fmaxf(fmaxf(sMLm[hh], sMLm[8 + hh]), fmaxf(sMLm[16 + hh], sMLm[24 + hh]));
        float L = sMLl[hh]      * __expf(sMLm[hh] - M)
                + sMLl[8 + hh]  * __expf(sMLm[8 + hh] - M)
                + sMLl[16 + hh] * __expf(sMLm[16 + hh] - M)
                + sMLl[24 + hh] * __expf(sMLm[24 + hh] - M);
        sOutF[e] = (sOutS[e] + ype + sRed[e]) / L + bpe[e];
    }
    __syncthreads();

    float y = 0.f;
    {
        const float* wo = Wo + (size_t)(half * 64) * 128 + e;
        #pragma unroll 8
        for (int ee = 0; ee < 64; ++ee) y += sOutF[half * 64 + ee] * wo[(size_t)ee * 128];
    }
    if (half) sRed[e] = y;
    __syncthreads();
    if (!half) out[bn * 128 + e] = y + sRed[e] + bo[e];
}

extern "C" void kernel_launch(void* const* d_in, const int* in_sizes, int n_in,
                              void* d_out, int out_size, void* d_ws, size_t ws_size,
                              hipStream_t stream)
{
    const float* query = (const float*)d_in[0];
    const float* key   = (const float*)d_in[1];
    const float* value = (const float*)d_in[2];
    const float* relpe = (const float*)d_in[3];
    const float* mask  = (const float*)d_in[4];
    const float* Wq  = (const float*)d_in[5];
    const float* bq  = (const float*)d_in[6];
    const float* Wk  = (const float*)d_in[7];
    const float* bk  = (const float*)d_in[8];
    const float* Wv  = (const float*)d_in[9];
    const float* bv  = (const float*)d_in[10];
    const float* Wpe = (const float*)d_in[11];
    const float* bpe = (const float*)d_in[12];
    const float* Wo  = (const float*)d_in[13];
    const float* bo  = (const float*)d_in[14];
    float* out = (float*)d_out;

    float* qf = (float*)d_ws;
    float* kf = qf + 16 * 256 * 128;
    float* vf = kf + 16 * 256 * 128;

    qkv_proj_kernel<<<dim3(768), dim3(256), 0, stream>>>(
        query, key, value, Wq, bq, Wk, bk, Wv, bv, qf, kf, vf);
    mha_main_kernel<<<dim3(4096), dim3(256), 0, stream>>>(
        relpe, mask, qf, kf, vf, Wpe, bpe, Wo, bo, out);
}